// Round 1
// baseline (2344.095 us; speedup 1.0000x reference)
//
#include <hip/hip_runtime.h>
#include <math.h>

#define C_DIM 1536
#define H_NUM 16
#define DH    96

// =====================================================================
// GEMM (NT): Y[M][Nn] = A[M][K] * W[Nn][K]^T + bias[Nn]
// 128x128 tile, BK=16, 256 threads, 8x8 micro as 2x2 blocks of 4.
// =====================================================================
#define GBM 128
#define GBN 128
#define GBK 16

__global__ __launch_bounds__(256)
void gemm_nt(const float* __restrict__ A, const float* __restrict__ W,
             const float* __restrict__ bias, float* __restrict__ Y,
             int M, int K, int Nn)
{
    __shared__ float As[GBK][132];   // [k][m], pad 132 (132%32==4 -> 2-way on stores)
    __shared__ float Bs[GBK][132];   // [k][n]

    const int tid = threadIdx.x;
    const int tx  = tid & 15, ty = tid >> 4;
    const int m0  = blockIdx.x * GBM;
    const int n0  = blockIdx.y * GBN;

    float acc[2][2][4][4];
    #pragma unroll
    for (int a = 0; a < 2; ++a)
        #pragma unroll
        for (int b = 0; b < 2; ++b)
            #pragma unroll
            for (int i = 0; i < 4; ++i)
                #pragma unroll
                for (int j = 0; j < 4; ++j) acc[a][b][i][j] = 0.f;

    for (int k0 = 0; k0 < K; k0 += GBK) {
        __syncthreads();   // previous compute done before overwriting LDS
        #pragma unroll
        for (int it = 0; it < 2; ++it) {
            const int f  = tid + 256 * it;      // 0..511
            const int r  = f >> 2;              // 0..127
            const int kg = (f & 3) * 4;         // 0,4,8,12
            float av[4];
            if (m0 + r < M) *(float4*)av = *(const float4*)&A[(size_t)(m0 + r) * K + k0 + kg];
            else { av[0] = av[1] = av[2] = av[3] = 0.f; }
            As[kg + 0][r] = av[0]; As[kg + 1][r] = av[1];
            As[kg + 2][r] = av[2]; As[kg + 3][r] = av[3];
            float wv[4];
            *(float4*)wv = *(const float4*)&W[(size_t)(n0 + r) * K + k0 + kg];
            Bs[kg + 0][r] = wv[0]; Bs[kg + 1][r] = wv[1];
            Bs[kg + 2][r] = wv[2]; Bs[kg + 3][r] = wv[3];
        }
        __syncthreads();
        #pragma unroll
        for (int kk = 0; kk < GBK; ++kk) {
            float a[8], b[8];
            *(float4*)&a[0] = *(const float4*)&As[kk][4 * ty];
            *(float4*)&a[4] = *(const float4*)&As[kk][64 + 4 * ty];
            *(float4*)&b[0] = *(const float4*)&Bs[kk][4 * tx];
            *(float4*)&b[4] = *(const float4*)&Bs[kk][64 + 4 * tx];
            #pragma unroll
            for (int ri = 0; ri < 2; ++ri)
                #pragma unroll
                for (int rj = 0; rj < 2; ++rj)
                    #pragma unroll
                    for (int ii = 0; ii < 4; ++ii)
                        #pragma unroll
                        for (int jj = 0; jj < 4; ++jj)
                            acc[ri][rj][ii][jj] += a[4 * ri + ii] * b[4 * rj + jj];
        }
    }

    #pragma unroll
    for (int ri = 0; ri < 2; ++ri)
        #pragma unroll
        for (int ii = 0; ii < 4; ++ii) {
            const int row = m0 + 64 * ri + 4 * ty + ii;
            if (row >= M) continue;
            #pragma unroll
            for (int rj = 0; rj < 2; ++rj) {
                const int col = n0 + 64 * rj + 4 * tx;
                float bv[4];
                *(float4*)bv = *(const float4*)&bias[col];
                float o[4];
                #pragma unroll
                for (int jj = 0; jj < 4; ++jj) o[jj] = acc[ri][rj][ii][jj] + bv[jj];
                *(float4*)&Y[(size_t)row * Nn + col] = *(float4*)o;
            }
        }
}

// =====================================================================
// RMSNorm (per head, Dh=96) + 3D RoPE, in place on Q and K ([N][C] layout).
// One thread per (token, head) vector. blockIdx.y: 0 -> Q, 1 -> K.
// =====================================================================
__global__ __launch_bounds__(256)
void rms_rope(float* __restrict__ q, float* __restrict__ k,
              const float* __restrict__ qw, const float* __restrict__ kw,
              const int* __restrict__ TTp, int Ntok)
{
    const int idx = blockIdx.x * 256 + threadIdx.x;
    if (idx >= Ntok * H_NUM) return;
    const int h = idx & (H_NUM - 1);
    const int n = idx >> 4;

    float* base;
    const float* w;
    if (blockIdx.y == 0) { base = q; w = qw; } else { base = k; w = kw; }
    float* p = base + (size_t)n * C_DIM + h * DH;

    float x[DH];
    #pragma unroll
    for (int i = 0; i < DH / 4; ++i) *(float4*)&x[4 * i] = *(const float4*)&p[4 * i];

    float ss = 0.f;
    #pragma unroll
    for (int i = 0; i < DH; ++i) ss += x[i] * x[i];
    const float r = rsqrtf(ss * (1.0f / DH) + 1e-6f);
    #pragma unroll
    for (int i = 0; i < DH; ++i) x[i] *= r * w[i];

    const int TT = *TTp;
    if (n >= TT) {
        const int pidx = n - TT;
        const int NT = Ntok - TT;
        int hh = 23, ww = 40;
        if      (NT == 2640) { hh = 22; ww = 40; }
        else if (NT == 1530) { hh = 17; ww = 30; }
        else if (NT == 6120) { hh = 34; ww = 60; }
        else if (NT ==  660) { hh = 11; ww = 20; }
        float pos[3];
        pos[0] = (float)(pidx / (hh * ww));
        pos[1] = (float)((pidx / ww) % hh);
        pos[2] = (float)(pidx % ww);
        #pragma unroll
        for (int c = 0; c < 3; ++c) {
            #pragma unroll
            for (int j = 0; j < 16; ++j) {
                // inv_freq = 10000^(-j/16) = 2^(-j*log2(10000)/16)
                const float invf = exp2f(-0.83048202373f * (float)j);
                const float ang  = pos[c] * invf;
                const float cs = cosf(ang), sn = sinf(ang);
                const float a = x[32 * c + j], b = x[32 * c + j + 16];
                x[32 * c + j]      = a * cs - b * sn;
                x[32 * c + j + 16] = a * sn + b * cs;
            }
        }
    }
    #pragma unroll
    for (int i = 0; i < DH / 4; ++i) *(float4*)&p[4 * i] = *(float4*)&x[4 * i];
}

// =====================================================================
// Flash attention, fp32. One block = (head, 64 query rows).
// LDS: Qs_t (swizzled transposed [d][i]), KVs (K swizzled transposed /
// V natural, time-multiplexed), Ps (P transposed, swizzled). 64 KiB exact.
// =====================================================================
__global__ __launch_bounds__(256)
void attn_fwd(const float* __restrict__ Q, const float* __restrict__ Kg,
              const float* __restrict__ V, float* __restrict__ O, int Ntok)
{
    __shared__ float Qs[DH * 64];    // swizzled transposed [d][i]
    __shared__ float KVs[DH * 64];   // K: swizzled transposed [d][j]; V: natural [j][d]
    __shared__ float Ps[64 * 64];    // swizzled transposed [j][i]

    const int tid = threadIdx.x;
    const int tx  = tid & 15, ty = tid >> 4;
    const int q0  = blockIdx.x * 64;
    const int hd  = blockIdx.y;
    const int hoff = hd * DH;

    // ---- load Q tile (transpose + XOR swizzle on 4-float groups) ----
    #pragma unroll
    for (int it = 0; it < 6; ++it) {
        const int f  = tid + 256 * it;     // 0..1535
        const int i  = f / 24;             // row 0..63
        const int dg = f % 24;             // d-group
        float val[4];
        const int n = q0 + i;
        if (n < Ntok) *(float4*)val = *(const float4*)&Q[(size_t)n * C_DIM + hoff + 4 * dg];
        else { val[0] = val[1] = val[2] = val[3] = 0.f; }
        const int g4 = 4 * ((i >> 2) ^ (dg & 15));
        const int b  = i & 3;
        #pragma unroll
        for (int d = 0; d < 4; ++d) Qs[(4 * dg + d) * 64 + g4 + b] = val[d];
    }

    float m_[4], l_[4], oacc[4][6];
    #pragma unroll
    for (int ii = 0; ii < 4; ++ii) {
        m_[ii] = -INFINITY; l_[ii] = 0.f;
        #pragma unroll
        for (int dd = 0; dd < 6; ++dd) oacc[ii][dd] = 0.f;
    }
    const float scale = 0.10206207261596577f;   // 96^-0.5

    for (int k0 = 0; k0 < Ntok; k0 += 64) {
        __syncthreads();   // prior PV reads of KVs/Ps done (and Qs ready 1st iter)
        // ---- load K tile (transposed, swizzled) ----
        #pragma unroll
        for (int it = 0; it < 6; ++it) {
            const int f  = tid + 256 * it;
            const int j  = f / 24;
            const int dg = f % 24;
            float val[4];
            const int n = k0 + j;
            if (n < Ntok) *(float4*)val = *(const float4*)&Kg[(size_t)n * C_DIM + hoff + 4 * dg];
            else { val[0] = val[1] = val[2] = val[3] = 0.f; }
            const int g4 = 4 * ((j >> 2) ^ (dg & 15));
            const int b  = j & 3;
            #pragma unroll
            for (int d = 0; d < 4; ++d) KVs[(4 * dg + d) * 64 + g4 + b] = val[d];
        }
        __syncthreads();   // K ready

        // ---- S = Q K^T (4x4 micro) ----
        float s[4][4];
        #pragma unroll
        for (int ii = 0; ii < 4; ++ii)
            #pragma unroll
            for (int jj = 0; jj < 4; ++jj) s[ii][jj] = 0.f;
        for (int dg = 0; dg < 24; ++dg) {
            const int gq = 4 * (ty ^ (dg & 15));
            const int gk = 4 * (tx ^ (dg & 15));
            #pragma unroll
            for (int d = 0; d < 4; ++d) {
                float qa[4], kb[4];
                *(float4*)qa = *(const float4*)&Qs[(4 * dg + d) * 64 + gq];
                *(float4*)kb = *(const float4*)&KVs[(4 * dg + d) * 64 + gk];
                #pragma unroll
                for (int ii = 0; ii < 4; ++ii)
                    #pragma unroll
                    for (int jj = 0; jj < 4; ++jj) s[ii][jj] += qa[ii] * kb[jj];
            }
        }

        // ---- online softmax (per row, redundant across the 16 tx lanes) ----
        bool vld[4];
        #pragma unroll
        for (int jj = 0; jj < 4; ++jj) vld[jj] = (k0 + 4 * tx + jj) < Ntok;
        #pragma unroll
        for (int ii = 0; ii < 4; ++ii) {
            float rmax = -1e30f;
            #pragma unroll
            for (int jj = 0; jj < 4; ++jj) {
                const float sv = vld[jj] ? s[ii][jj] * scale : -1e30f;
                s[ii][jj] = sv;
                rmax = fmaxf(rmax, sv);
            }
            rmax = fmaxf(rmax, __shfl_xor(rmax, 1, 16));
            rmax = fmaxf(rmax, __shfl_xor(rmax, 2, 16));
            rmax = fmaxf(rmax, __shfl_xor(rmax, 4, 16));
            rmax = fmaxf(rmax, __shfl_xor(rmax, 8, 16));
            const float mnew  = fmaxf(m_[ii], rmax);
            const float alpha = __expf(m_[ii] - mnew);
            float pr[4]; float rsum = 0.f;
            #pragma unroll
            for (int jj = 0; jj < 4; ++jj) {
                pr[jj] = vld[jj] ? __expf(s[ii][jj] - mnew) : 0.f;
                rsum += pr[jj];
            }
            rsum += __shfl_xor(rsum, 1, 16);
            rsum += __shfl_xor(rsum, 2, 16);
            rsum += __shfl_xor(rsum, 4, 16);
            rsum += __shfl_xor(rsum, 8, 16);
            l_[ii] = l_[ii] * alpha + rsum;
            m_[ii] = mnew;
            #pragma unroll
            for (int dd = 0; dd < 6; ++dd) oacc[ii][dd] *= alpha;
            #pragma unroll
            for (int jj = 0; jj < 4; ++jj)
                Ps[(4 * tx + jj) * 64 + 4 * (ty ^ tx) + ii] = pr[jj];
        }
        __syncthreads();   // P written, all K reads done

        // ---- load V tile (natural [j][96]) into same buffer ----
        #pragma unroll
        for (int it = 0; it < 6; ++it) {
            const int f  = tid + 256 * it;
            const int j  = f / 24;
            const int dg = f % 24;
            float val[4];
            const int n = k0 + j;
            if (n < Ntok) *(float4*)val = *(const float4*)&V[(size_t)n * C_DIM + hoff + 4 * dg];
            else { val[0] = val[1] = val[2] = val[3] = 0.f; }
            *(float4*)&KVs[j * 96 + 4 * dg] = *(float4*)val;
        }
        __syncthreads();   // V ready

        // ---- O += P V (rows 4ty+ii, cols 6tx+dd) ----
        #pragma unroll 4
        for (int j = 0; j < 64; ++j) {
            float p4[4];
            *(float4*)p4 = *(const float4*)&Ps[j * 64 + 4 * (ty ^ ((j >> 2) & 15))];
            float vv[6];
            *(float2*)&vv[0] = *(const float2*)&KVs[j * 96 + 6 * tx];
            *(float2*)&vv[2] = *(const float2*)&KVs[j * 96 + 6 * tx + 2];
            *(float2*)&vv[4] = *(const float2*)&KVs[j * 96 + 6 * tx + 4];
            #pragma unroll
            for (int ii = 0; ii < 4; ++ii)
                #pragma unroll
                for (int dd = 0; dd < 6; ++dd) oacc[ii][dd] += p4[ii] * vv[dd];
        }
    }

    // ---- epilogue: O / l ----
    #pragma unroll
    for (int ii = 0; ii < 4; ++ii) {
        const int n = q0 + 4 * ty + ii;
        if (n >= Ntok) continue;
        const float rl = 1.0f / l_[ii];
        float* op = &O[(size_t)n * C_DIM + hoff + 6 * tx];
        float o2[2];
        o2[0] = oacc[ii][0] * rl; o2[1] = oacc[ii][1] * rl; *(float2*)&op[0] = *(float2*)o2;
        o2[0] = oacc[ii][2] * rl; o2[1] = oacc[ii][3] * rl; *(float2*)&op[2] = *(float2*)o2;
        o2[0] = oacc[ii][4] * rl; o2[1] = oacc[ii][5] * rl; *(float2*)&op[4] = *(float2*)o2;
    }
}

// =====================================================================
extern "C" void kernel_launch(void* const* d_in, const int* in_sizes, int n_in,
                              void* d_out, int out_size, void* d_ws, size_t ws_size,
                              hipStream_t stream)
{
    const float* x   = (const float*)d_in[0];
    const float* Wq  = (const float*)d_in[1];
    const float* bq  = (const float*)d_in[2];
    const float* Wk  = (const float*)d_in[3];
    const float* bk  = (const float*)d_in[4];
    const float* Wv  = (const float*)d_in[5];
    const float* bv  = (const float*)d_in[6];
    const float* qnw = (const float*)d_in[7];
    const float* knw = (const float*)d_in[8];
    const float* Wp  = (const float*)d_in[9];
    const float* bp  = (const float*)d_in[10];
    const int*   TTp = (const int*)d_in[11];

    const int Ntok = in_sizes[0] / C_DIM;     // 2866
    float* out = (float*)d_out;

    // Q lives in d_out (fully overwritten by final GEMM afterwards);
    // K, V, attention-O in workspace: 3 * N * C * 4 B = 52.8 MB.
    float* qbuf = out;
    float* kbuf = (float*)d_ws;
    float* vbuf = kbuf + (size_t)Ntok * C_DIM;
    float* obuf = vbuf + (size_t)Ntok * C_DIM;

    dim3 ggrid((Ntok + GBM - 1) / GBM, C_DIM / GBN);
    gemm_nt<<<ggrid, 256, 0, stream>>>(x, Wq, bq, qbuf, Ntok, C_DIM, C_DIM);
    gemm_nt<<<ggrid, 256, 0, stream>>>(x, Wk, bk, kbuf, Ntok, C_DIM, C_DIM);
    gemm_nt<<<ggrid, 256, 0, stream>>>(x, Wv, bv, vbuf, Ntok, C_DIM, C_DIM);

    const int nv = Ntok * H_NUM;
    rms_rope<<<dim3((nv + 255) / 256, 2), 256, 0, stream>>>(qbuf, kbuf, qnw, knw, TTp, Ntok);

    attn_fwd<<<dim3((Ntok + 63) / 64, H_NUM), 256, 0, stream>>>(qbuf, kbuf, vbuf, obuf, Ntok);

    gemm_nt<<<ggrid, 256, 0, stream>>>(obuf, Wp, bp, out, Ntok, C_DIM, C_DIM);
}

// Round 2
// 1504.844 us; speedup vs baseline: 1.5577x; 1.5577x over previous
//
#include <hip/hip_runtime.h>
#include <math.h>

#define C_DIM 1536
#define H_NUM 16
#define DH    96

typedef __attribute__((ext_vector_type(4))) float  f32x4;
typedef __attribute__((ext_vector_type(8))) short  bf16x8;   // 8 bf16 = 4 VGPRs

// =====================================================================
// Split fp32 -> (hi, lo) bf16 pair.  x ~= hi + lo, |err| <~ 2^-18 |x|.
// =====================================================================
__device__ __forceinline__ unsigned short f2bf_rne(float f) {
    unsigned u = __float_as_uint(f);
    unsigned r = (u + 0x7FFFu + ((u >> 16) & 1u)) >> 16;
    return (unsigned short)r;
}

__global__ __launch_bounds__(256)
void cvt_split(const float* __restrict__ in, unsigned short* __restrict__ hi,
               unsigned short* __restrict__ lo, int n4)   // n4 = n/4
{
    const int i = blockIdx.x * 256 + threadIdx.x;
    if (i >= n4) return;
    float4 v = *(const float4*)&in[4 * i];
    unsigned short h[4], l[4];
    float vv[4] = {v.x, v.y, v.z, v.w};
    #pragma unroll
    for (int j = 0; j < 4; ++j) {
        h[j] = f2bf_rne(vv[j]);
        float hf = __uint_as_float(((unsigned)h[j]) << 16);
        l[j] = f2bf_rne(vv[j] - hf);
    }
    *(ushort4*)&hi[4 * i] = *(ushort4*)h;
    *(ushort4*)&lo[4 * i] = *(ushort4*)l;
}

// =====================================================================
// Split-bf16 MFMA GEMM (NT): Y[M][1536] = A[M][1536] * W[1536][1536]^T + b
// 128x128 tile, BK=32, 256 threads = 4 waves (wave -> 64x64 quadrant,
// 4x4 grid of 16x16x32 MFMA tiles, 3 MFMAs per tile: hh + lh + hl).
// LDS chunks XOR-swizzled so frag ds_read_b128 is 2-way (free).
// blockIdx.z selects one of up to 3 (W, bias, Y) problem instances.
// =====================================================================
__global__ __launch_bounds__(256)
void gemm_mfma(const unsigned short* __restrict__ Ahi,
               const unsigned short* __restrict__ Alo,
               const unsigned short* W0h, const unsigned short* W0l,
               const float* b0, float* Y0,
               const unsigned short* W1h, const unsigned short* W1l,
               const float* b1, float* Y1,
               const unsigned short* W2h, const unsigned short* W2l,
               const float* b2, float* Y2,
               int M)
{
    __shared__ unsigned short ldsAh[128 * 32];
    __shared__ unsigned short ldsAl[128 * 32];
    __shared__ unsigned short ldsBh[128 * 32];
    __shared__ unsigned short ldsBl[128 * 32];

    const unsigned short* Wh;
    const unsigned short* Wl;
    const float* bias;
    float* Y;
    if (blockIdx.z == 0)      { Wh = W0h; Wl = W0l; bias = b0; Y = Y0; }
    else if (blockIdx.z == 1) { Wh = W1h; Wl = W1l; bias = b1; Y = Y1; }
    else                      { Wh = W2h; Wl = W2l; bias = b2; Y = Y2; }

    const int t   = threadIdx.x;
    const int m0  = blockIdx.x * 128;
    const int n0  = blockIdx.y * 128;

    // ---- staging geometry (per thread: 2 chunks per matrix) ----
    const int r0 = t >> 2;            // rows 0..63   (it=0) ; +64 for it=1
    const int c0 = t & 3;             // k-chunk 0..3 (8 bf16 each)
    const int sw0 = (r0 >> 1) & 3;
    const int sw1 = ((r0 + 64) >> 1) & 3;
    const int ldst0 = r0 * 32        + 8 * (c0 ^ sw0);
    const int ldst1 = (r0 + 64) * 32 + 8 * (c0 ^ sw1);
    const bool av0 = (m0 + r0)      < M;
    const bool av1 = (m0 + r0 + 64) < M;
    const size_t gA0 = (size_t)(m0 + r0)      * C_DIM + 8 * c0;
    const size_t gA1 = (size_t)(m0 + r0 + 64) * C_DIM + 8 * c0;
    const size_t gB0 = (size_t)(n0 + r0)      * C_DIM + 8 * c0;
    const size_t gB1 = (size_t)(n0 + r0 + 64) * C_DIM + 8 * c0;

    // ---- fragment geometry ----
    const int lane = t & 63;
    const int wv   = t >> 6;
    const int wm   = wv & 1, wn = wv >> 1;
    const int lrow = lane & 15;
    const int quad = lane >> 4;
    const int pc   = quad ^ ((lrow >> 1) & 3);    // swizzled chunk, same for all tiles
    int aoff[4], boff[4];
    #pragma unroll
    for (int i = 0; i < 4; ++i) {
        aoff[i] = (64 * wm + 16 * i + lrow) * 32 + 8 * pc;
        boff[i] = (64 * wn + 16 * i + lrow) * 32 + 8 * pc;
    }

    f32x4 acc[4][4];
    #pragma unroll
    for (int i = 0; i < 4; ++i)
        #pragma unroll
        for (int j = 0; j < 4; ++j) acc[i][j] = (f32x4)0.f;

    const float4 zero4 = make_float4(0.f, 0.f, 0.f, 0.f);

    for (int k0 = 0; k0 < C_DIM; k0 += 32) {
        __syncthreads();
        float4 vah0 = av0 ? *(const float4*)&Ahi[gA0 + k0] : zero4;
        float4 vah1 = av1 ? *(const float4*)&Ahi[gA1 + k0] : zero4;
        float4 val0 = av0 ? *(const float4*)&Alo[gA0 + k0] : zero4;
        float4 val1 = av1 ? *(const float4*)&Alo[gA1 + k0] : zero4;
        float4 vbh0 = *(const float4*)&Wh[gB0 + k0];
        float4 vbh1 = *(const float4*)&Wh[gB1 + k0];
        float4 vbl0 = *(const float4*)&Wl[gB0 + k0];
        float4 vbl1 = *(const float4*)&Wl[gB1 + k0];
        *(float4*)&ldsAh[ldst0] = vah0;  *(float4*)&ldsAh[ldst1] = vah1;
        *(float4*)&ldsAl[ldst0] = val0;  *(float4*)&ldsAl[ldst1] = val1;
        *(float4*)&ldsBh[ldst0] = vbh0;  *(float4*)&ldsBh[ldst1] = vbh1;
        *(float4*)&ldsBl[ldst0] = vbl0;  *(float4*)&ldsBl[ldst1] = vbl1;
        __syncthreads();

        bf16x8 ah[4], al[4], bh[4], bl[4];
        #pragma unroll
        for (int i = 0; i < 4; ++i) {
            ah[i] = *(const bf16x8*)&ldsAh[aoff[i]];
            al[i] = *(const bf16x8*)&ldsAl[aoff[i]];
            bh[i] = *(const bf16x8*)&ldsBh[boff[i]];
            bl[i] = *(const bf16x8*)&ldsBl[boff[i]];
        }
        #pragma unroll
        for (int i = 0; i < 4; ++i)
            #pragma unroll
            for (int j = 0; j < 4; ++j) {
                acc[i][j] = __builtin_amdgcn_mfma_f32_16x16x32_bf16(ah[i], bh[j], acc[i][j], 0, 0, 0);
                acc[i][j] = __builtin_amdgcn_mfma_f32_16x16x32_bf16(al[i], bh[j], acc[i][j], 0, 0, 0);
                acc[i][j] = __builtin_amdgcn_mfma_f32_16x16x32_bf16(ah[i], bl[j], acc[i][j], 0, 0, 0);
            }
    }

    // ---- epilogue: C/D mapping col = lane&15, row = quad*4 + p ----
    float bv[4];
    #pragma unroll
    for (int j = 0; j < 4; ++j) bv[j] = bias[n0 + 64 * wn + 16 * j + lrow];
    #pragma unroll
    for (int i = 0; i < 4; ++i) {
        const int rbase = m0 + 64 * wm + 16 * i + 4 * quad;
        #pragma unroll
        for (int p = 0; p < 4; ++p) {
            const int row = rbase + p;
            if (row >= M) continue;
            #pragma unroll
            for (int j = 0; j < 4; ++j) {
                const int col = n0 + 64 * wn + 16 * j + lrow;
                Y[(size_t)row * C_DIM + col] = acc[i][j][p] + bv[j];
            }
        }
    }
}

// =====================================================================
// RMSNorm (per head, Dh=96) + 3D RoPE, in place on Q and K ([N][C]).
// =====================================================================
__global__ __launch_bounds__(256)
void rms_rope(float* __restrict__ q, float* __restrict__ k,
              const float* __restrict__ qw, const float* __restrict__ kw,
              const int* __restrict__ TTp, int Ntok)
{
    const int idx = blockIdx.x * 256 + threadIdx.x;
    if (idx >= Ntok * H_NUM) return;
    const int h = idx & (H_NUM - 1);
    const int n = idx >> 4;

    float* base;
    const float* w;
    if (blockIdx.y == 0) { base = q; w = qw; } else { base = k; w = kw; }
    float* p = base + (size_t)n * C_DIM + h * DH;

    float x[DH];
    #pragma unroll
    for (int i = 0; i < DH / 4; ++i) *(float4*)&x[4 * i] = *(const float4*)&p[4 * i];

    float ss = 0.f;
    #pragma unroll
    for (int i = 0; i < DH; ++i) ss += x[i] * x[i];
    const float r = rsqrtf(ss * (1.0f / DH) + 1e-6f);
    #pragma unroll
    for (int i = 0; i < DH; ++i) x[i] *= r * w[i];

    const int TT = *TTp;
    if (n >= TT) {
        const int pidx = n - TT;
        const int NT = Ntok - TT;
        int hh = 23, ww = 40;
        if      (NT == 2640) { hh = 22; ww = 40; }
        else if (NT == 1530) { hh = 17; ww = 30; }
        else if (NT == 6120) { hh = 34; ww = 60; }
        else if (NT ==  660) { hh = 11; ww = 20; }
        float pos[3];
        pos[0] = (float)(pidx / (hh * ww));
        pos[1] = (float)((pidx / ww) % hh);
        pos[2] = (float)(pidx % ww);
        #pragma unroll
        for (int c = 0; c < 3; ++c) {
            #pragma unroll
            for (int j = 0; j < 16; ++j) {
                const float invf = exp2f(-0.83048202373f * (float)j);
                const float ang  = pos[c] * invf;
                const float cs = cosf(ang), sn = sinf(ang);
                const float a = x[32 * c + j], b = x[32 * c + j + 16];
                x[32 * c + j]      = a * cs - b * sn;
                x[32 * c + j + 16] = a * sn + b * cs;
            }
        }
    }
    #pragma unroll
    for (int i = 0; i < DH / 4; ++i) *(float4*)&p[4 * i] = *(float4*)&x[4 * i];
}

// =====================================================================
// Flash attention, fp32 (unchanged from round 1 — MFMA rewrite next).
// =====================================================================
__global__ __launch_bounds__(256)
void attn_fwd(const float* __restrict__ Q, const float* __restrict__ Kg,
              const float* __restrict__ V, float* __restrict__ O, int Ntok)
{
    __shared__ float Qs[DH * 64];
    __shared__ float KVs[DH * 64];
    __shared__ float Ps[64 * 64];

    const int tid = threadIdx.x;
    const int tx  = tid & 15, ty = tid >> 4;
    const int q0  = blockIdx.x * 64;
    const int hoff = blockIdx.y * DH;

    #pragma unroll
    for (int it = 0; it < 6; ++it) {
        const int f  = tid + 256 * it;
        const int i  = f / 24;
        const int dg = f % 24;
        float val[4];
        const int n = q0 + i;
        if (n < Ntok) *(float4*)val = *(const float4*)&Q[(size_t)n * C_DIM + hoff + 4 * dg];
        else { val[0] = val[1] = val[2] = val[3] = 0.f; }
        const int g4 = 4 * ((i >> 2) ^ (dg & 15));
        const int b  = i & 3;
        #pragma unroll
        for (int d = 0; d < 4; ++d) Qs[(4 * dg + d) * 64 + g4 + b] = val[d];
    }

    float m_[4], l_[4], oacc[4][6];
    #pragma unroll
    for (int ii = 0; ii < 4; ++ii) {
        m_[ii] = -INFINITY; l_[ii] = 0.f;
        #pragma unroll
        for (int dd = 0; dd < 6; ++dd) oacc[ii][dd] = 0.f;
    }
    const float scale = 0.10206207261596577f;

    for (int k0 = 0; k0 < Ntok; k0 += 64) {
        __syncthreads();
        #pragma unroll
        for (int it = 0; it < 6; ++it) {
            const int f  = tid + 256 * it;
            const int j  = f / 24;
            const int dg = f % 24;
            float val[4];
            const int n = k0 + j;
            if (n < Ntok) *(float4*)val = *(const float4*)&Kg[(size_t)n * C_DIM + hoff + 4 * dg];
            else { val[0] = val[1] = val[2] = val[3] = 0.f; }
            const int g4 = 4 * ((j >> 2) ^ (dg & 15));
            const int b  = j & 3;
            #pragma unroll
            for (int d = 0; d < 4; ++d) KVs[(4 * dg + d) * 64 + g4 + b] = val[d];
        }
        __syncthreads();

        float s[4][4];
        #pragma unroll
        for (int ii = 0; ii < 4; ++ii)
            #pragma unroll
            for (int jj = 0; jj < 4; ++jj) s[ii][jj] = 0.f;
        for (int dg = 0; dg < 24; ++dg) {
            const int gq = 4 * (ty ^ (dg & 15));
            const int gk = 4 * (tx ^ (dg & 15));
            #pragma unroll
            for (int d = 0; d < 4; ++d) {
                float qa[4], kb[4];
                *(float4*)qa = *(const float4*)&Qs[(4 * dg + d) * 64 + gq];
                *(float4*)kb = *(const float4*)&KVs[(4 * dg + d) * 64 + gk];
                #pragma unroll
                for (int ii = 0; ii < 4; ++ii)
                    #pragma unroll
                    for (int jj = 0; jj < 4; ++jj) s[ii][jj] += qa[ii] * kb[jj];
            }
        }

        bool vld[4];
        #pragma unroll
        for (int jj = 0; jj < 4; ++jj) vld[jj] = (k0 + 4 * tx + jj) < Ntok;
        #pragma unroll
        for (int ii = 0; ii < 4; ++ii) {
            float rmax = -1e30f;
            #pragma unroll
            for (int jj = 0; jj < 4; ++jj) {
                const float sv = vld[jj] ? s[ii][jj] * scale : -1e30f;
                s[ii][jj] = sv;
                rmax = fmaxf(rmax, sv);
            }
            rmax = fmaxf(rmax, __shfl_xor(rmax, 1, 16));
            rmax = fmaxf(rmax, __shfl_xor(rmax, 2, 16));
            rmax = fmaxf(rmax, __shfl_xor(rmax, 4, 16));
            rmax = fmaxf(rmax, __shfl_xor(rmax, 8, 16));
            const float mnew  = fmaxf(m_[ii], rmax);
            const float alpha = __expf(m_[ii] - mnew);
            float pr[4]; float rsum = 0.f;
            #pragma unroll
            for (int jj = 0; jj < 4; ++jj) {
                pr[jj] = vld[jj] ? __expf(s[ii][jj] - mnew) : 0.f;
                rsum += pr[jj];
            }
            rsum += __shfl_xor(rsum, 1, 16);
            rsum += __shfl_xor(rsum, 2, 16);
            rsum += __shfl_xor(rsum, 4, 16);
            rsum += __shfl_xor(rsum, 8, 16);
            l_[ii] = l_[ii] * alpha + rsum;
            m_[ii] = mnew;
            #pragma unroll
            for (int dd = 0; dd < 6; ++dd) oacc[ii][dd] *= alpha;
            #pragma unroll
            for (int jj = 0; jj < 4; ++jj)
                Ps[(4 * tx + jj) * 64 + 4 * (ty ^ tx) + ii] = pr[jj];
        }
        __syncthreads();

        #pragma unroll
        for (int it = 0; it < 6; ++it) {
            const int f  = tid + 256 * it;
            const int j  = f / 24;
            const int dg = f % 24;
            float val[4];
            const int n = k0 + j;
            if (n < Ntok) *(float4*)val = *(const float4*)&V[(size_t)n * C_DIM + hoff + 4 * dg];
            else { val[0] = val[1] = val[2] = val[3] = 0.f; }
            *(float4*)&KVs[j * 96 + 4 * dg] = *(float4*)val;
        }
        __syncthreads();

        #pragma unroll 4
        for (int j = 0; j < 64; ++j) {
            float p4[4];
            *(float4*)p4 = *(const float4*)&Ps[j * 64 + 4 * (ty ^ ((j >> 2) & 15))];
            float vv[6];
            *(float2*)&vv[0] = *(const float2*)&KVs[j * 96 + 6 * tx];
            *(float2*)&vv[2] = *(const float2*)&KVs[j * 96 + 6 * tx + 2];
            *(float2*)&vv[4] = *(const float2*)&KVs[j * 96 + 6 * tx + 4];
            #pragma unroll
            for (int ii = 0; ii < 4; ++ii)
                #pragma unroll
                for (int dd = 0; dd < 6; ++dd) oacc[ii][dd] += p4[ii] * vv[dd];
        }
    }

    #pragma unroll
    for (int ii = 0; ii < 4; ++ii) {
        const int n = q0 + 4 * ty + ii;
        if (n >= Ntok) continue;
        const float rl = 1.0f / l_[ii];
        float* op = &O[(size_t)n * C_DIM + hoff + 6 * tx];
        float o2[2];
        o2[0] = oacc[ii][0] * rl; o2[1] = oacc[ii][1] * rl; *(float2*)&op[0] = *(float2*)o2;
        o2[0] = oacc[ii][2] * rl; o2[1] = oacc[ii][3] * rl; *(float2*)&op[2] = *(float2*)o2;
        o2[0] = oacc[ii][4] * rl; o2[1] = oacc[ii][5] * rl; *(float2*)&op[4] = *(float2*)o2;
    }
}

// =====================================================================
extern "C" void kernel_launch(void* const* d_in, const int* in_sizes, int n_in,
                              void* d_out, int out_size, void* d_ws, size_t ws_size,
                              hipStream_t stream)
{
    const float* x   = (const float*)d_in[0];
    const float* Wq  = (const float*)d_in[1];
    const float* bq  = (const float*)d_in[2];
    const float* Wk  = (const float*)d_in[3];
    const float* bk  = (const float*)d_in[4];
    const float* Wv  = (const float*)d_in[5];
    const float* bv  = (const float*)d_in[6];
    const float* qnw = (const float*)d_in[7];
    const float* knw = (const float*)d_in[8];
    const float* Wp  = (const float*)d_in[9];
    const float* bp  = (const float*)d_in[10];
    const int*   TTp = (const int*)d_in[11];

    const int Ntok = in_sizes[0] / C_DIM;        // 2866
    const size_t NC = (size_t)Ntok * C_DIM;      // 4.40M
    const size_t CC = (size_t)C_DIM * C_DIM;     // 2.36M
    float* out = (float*)d_out;

    // workspace layout (~90 MB):
    float*          kbuf = (float*)d_ws;                      // NC f32
    float*          vbuf = kbuf + NC;                         // NC f32
    unsigned short* xhi  = (unsigned short*)(vbuf + NC);      // NC bf16
    unsigned short* xlo  = xhi + NC;                          // NC bf16
    unsigned short* wsp  = xlo + NC;                          // 8 * CC bf16
    unsigned short* wqh = wsp + 0 * CC, *wql = wsp + 1 * CC;
    unsigned short* wkh = wsp + 2 * CC, *wkl = wsp + 3 * CC;
    unsigned short* wvh = wsp + 4 * CC, *wvl = wsp + 5 * CC;
    unsigned short* wph = wsp + 6 * CC, *wpl = wsp + 7 * CC;
    float*          qbuf = out;                               // NC f32 (d_out)
    float*          obuf = (float*)xhi;                       // alias: x dead after QKV
    unsigned short* ohi  = (unsigned short*)kbuf;             // alias: K dead after attn
    unsigned short* olo  = ohi + NC;

    // 1) split conversions
    cvt_split<<<dim3((NC / 4 + 255) / 256), 256, 0, stream>>>(x,  xhi, xlo, (int)(NC / 4));
    cvt_split<<<dim3((CC / 4 + 255) / 256), 256, 0, stream>>>(Wq, wqh, wql, (int)(CC / 4));
    cvt_split<<<dim3((CC / 4 + 255) / 256), 256, 0, stream>>>(Wk, wkh, wkl, (int)(CC / 4));
    cvt_split<<<dim3((CC / 4 + 255) / 256), 256, 0, stream>>>(Wv, wvh, wvl, (int)(CC / 4));
    cvt_split<<<dim3((CC / 4 + 255) / 256), 256, 0, stream>>>(Wp, wph, wpl, (int)(CC / 4));

    // 2) fused QKV projection (z = 0,1,2)
    dim3 qkvgrid((Ntok + 127) / 128, C_DIM / 128, 3);
    gemm_mfma<<<qkvgrid, 256, 0, stream>>>(xhi, xlo,
        wqh, wql, bq, qbuf,
        wkh, wkl, bk, kbuf,
        wvh, wvl, bv, vbuf, Ntok);

    // 3) RMSNorm + RoPE on q, k
    const int nv = Ntok * H_NUM;
    rms_rope<<<dim3((nv + 255) / 256, 2), 256, 0, stream>>>(qbuf, kbuf, qnw, knw, TTp, Ntok);

    // 4) attention (fp32)
    attn_fwd<<<dim3((Ntok + 63) / 64, H_NUM), 256, 0, stream>>>(qbuf, kbuf, vbuf, obuf, Ntok);

    // 5) split O, output projection
    cvt_split<<<dim3((NC / 4 + 255) / 256), 256, 0, stream>>>(obuf, ohi, olo, (int)(NC / 4));
    dim3 pgrid((Ntok + 127) / 128, C_DIM / 128, 1);
    gemm_mfma<<<pgrid, 256, 0, stream>>>(ohi, olo,
        wph, wpl, bp, out,
        wph, wpl, bp, out,
        wph, wpl, bp, out, Ntok);
}

// Round 3
// 629.655 us; speedup vs baseline: 3.7228x; 2.3899x over previous
//
#include <hip/hip_runtime.h>
#include <hip/hip_bf16.h>
#include <math.h>

#define C_DIM 1536
#define H_NUM 16
#define DH    96

typedef __attribute__((ext_vector_type(4))) float  f32x4;
typedef __attribute__((ext_vector_type(8))) short  bf16x8;   // 8 bf16 = 4 VGPRs

// =====================================================================
// fp32 -> bf16 RNE, and split helpers
// =====================================================================
__device__ __forceinline__ unsigned short f2bf_rne(float f) {
    unsigned u = __float_as_uint(f);
    unsigned r = (u + 0x7FFFu + ((u >> 16) & 1u)) >> 16;
    return (unsigned short)r;
}
__device__ __forceinline__ float bf2f(unsigned short h) {
    return __uint_as_float(((unsigned)h) << 16);
}

__global__ __launch_bounds__(256)
void cvt_split(const float* __restrict__ in, unsigned short* __restrict__ hi,
               unsigned short* __restrict__ lo, int n4)   // n4 = n/4
{
    const int i = blockIdx.x * 256 + threadIdx.x;
    if (i >= n4) return;
    float4 v = *(const float4*)&in[4 * i];
    unsigned short h[4], l[4];
    float vv[4] = {v.x, v.y, v.z, v.w};
    #pragma unroll
    for (int j = 0; j < 4; ++j) {
        h[j] = f2bf_rne(vv[j]);
        l[j] = f2bf_rne(vv[j] - bf2f(h[j]));
    }
    *(ushort4*)&hi[4 * i] = *(ushort4*)h;
    *(ushort4*)&lo[4 * i] = *(ushort4*)l;
}

// =====================================================================
// Split-bf16 MFMA GEMM (NT) — unchanged from round 1 (validated).
// =====================================================================
__global__ __launch_bounds__(256)
void gemm_mfma(const unsigned short* __restrict__ Ahi,
               const unsigned short* __restrict__ Alo,
               const unsigned short* W0h, const unsigned short* W0l,
               const float* b0, float* Y0,
               const unsigned short* W1h, const unsigned short* W1l,
               const float* b1, float* Y1,
               const unsigned short* W2h, const unsigned short* W2l,
               const float* b2, float* Y2,
               int M)
{
    __shared__ unsigned short ldsAh[128 * 32];
    __shared__ unsigned short ldsAl[128 * 32];
    __shared__ unsigned short ldsBh[128 * 32];
    __shared__ unsigned short ldsBl[128 * 32];

    const unsigned short* Wh;
    const unsigned short* Wl;
    const float* bias;
    float* Y;
    if (blockIdx.z == 0)      { Wh = W0h; Wl = W0l; bias = b0; Y = Y0; }
    else if (blockIdx.z == 1) { Wh = W1h; Wl = W1l; bias = b1; Y = Y1; }
    else                      { Wh = W2h; Wl = W2l; bias = b2; Y = Y2; }

    const int t   = threadIdx.x;
    const int m0  = blockIdx.x * 128;
    const int n0  = blockIdx.y * 128;

    const int r0 = t >> 2;
    const int c0 = t & 3;
    const int sw0 = (r0 >> 1) & 3;
    const int sw1 = ((r0 + 64) >> 1) & 3;
    const int ldst0 = r0 * 32        + 8 * (c0 ^ sw0);
    const int ldst1 = (r0 + 64) * 32 + 8 * (c0 ^ sw1);
    const bool av0 = (m0 + r0)      < M;
    const bool av1 = (m0 + r0 + 64) < M;
    const size_t gA0 = (size_t)(m0 + r0)      * C_DIM + 8 * c0;
    const size_t gA1 = (size_t)(m0 + r0 + 64) * C_DIM + 8 * c0;
    const size_t gB0 = (size_t)(n0 + r0)      * C_DIM + 8 * c0;
    const size_t gB1 = (size_t)(n0 + r0 + 64) * C_DIM + 8 * c0;

    const int lane = t & 63;
    const int wv   = t >> 6;
    const int wm   = wv & 1, wn = wv >> 1;
    const int lrow = lane & 15;
    const int quad = lane >> 4;
    const int pc   = quad ^ ((lrow >> 1) & 3);
    int aoff[4], boff[4];
    #pragma unroll
    for (int i = 0; i < 4; ++i) {
        aoff[i] = (64 * wm + 16 * i + lrow) * 32 + 8 * pc;
        boff[i] = (64 * wn + 16 * i + lrow) * 32 + 8 * pc;
    }

    f32x4 acc[4][4];
    #pragma unroll
    for (int i = 0; i < 4; ++i)
        #pragma unroll
        for (int j = 0; j < 4; ++j) acc[i][j] = (f32x4)0.f;

    const float4 zero4 = make_float4(0.f, 0.f, 0.f, 0.f);

    for (int k0 = 0; k0 < C_DIM; k0 += 32) {
        __syncthreads();
        float4 vah0 = av0 ? *(const float4*)&Ahi[gA0 + k0] : zero4;
        float4 vah1 = av1 ? *(const float4*)&Ahi[gA1 + k0] : zero4;
        float4 val0 = av0 ? *(const float4*)&Alo[gA0 + k0] : zero4;
        float4 val1 = av1 ? *(const float4*)&Alo[gA1 + k0] : zero4;
        float4 vbh0 = *(const float4*)&Wh[gB0 + k0];
        float4 vbh1 = *(const float4*)&Wh[gB1 + k0];
        float4 vbl0 = *(const float4*)&Wl[gB0 + k0];
        float4 vbl1 = *(const float4*)&Wl[gB1 + k0];
        *(float4*)&ldsAh[ldst0] = vah0;  *(float4*)&ldsAh[ldst1] = vah1;
        *(float4*)&ldsAl[ldst0] = val0;  *(float4*)&ldsAl[ldst1] = val1;
        *(float4*)&ldsBh[ldst0] = vbh0;  *(float4*)&ldsBh[ldst1] = vbh1;
        *(float4*)&ldsBl[ldst0] = vbl0;  *(float4*)&ldsBl[ldst1] = vbl1;
        __syncthreads();

        bf16x8 ah[4], al[4], bh[4], bl[4];
        #pragma unroll
        for (int i = 0; i < 4; ++i) {
            ah[i] = *(const bf16x8*)&ldsAh[aoff[i]];
            al[i] = *(const bf16x8*)&ldsAl[aoff[i]];
            bh[i] = *(const bf16x8*)&ldsBh[boff[i]];
            bl[i] = *(const bf16x8*)&ldsBl[boff[i]];
        }
        #pragma unroll
        for (int i = 0; i < 4; ++i)
            #pragma unroll
            for (int j = 0; j < 4; ++j) {
                acc[i][j] = __builtin_amdgcn_mfma_f32_16x16x32_bf16(ah[i], bh[j], acc[i][j], 0, 0, 0);
                acc[i][j] = __builtin_amdgcn_mfma_f32_16x16x32_bf16(al[i], bh[j], acc[i][j], 0, 0, 0);
                acc[i][j] = __builtin_amdgcn_mfma_f32_16x16x32_bf16(ah[i], bl[j], acc[i][j], 0, 0, 0);
            }
    }

    float bv[4];
    #pragma unroll
    for (int j = 0; j < 4; ++j) bv[j] = bias[n0 + 64 * wn + 16 * j + lrow];
    #pragma unroll
    for (int i = 0; i < 4; ++i) {
        const int rbase = m0 + 64 * wm + 16 * i + 4 * quad;
        #pragma unroll
        for (int p = 0; p < 4; ++p) {
            const int row = rbase + p;
            if (row >= M) continue;
            #pragma unroll
            for (int j = 0; j < 4; ++j) {
                const int col = n0 + 64 * wn + 16 * j + lrow;
                Y[(size_t)row * C_DIM + col] = acc[i][j][p] + bv[j];
            }
        }
    }
}

// =====================================================================
// RMSNorm + 3D RoPE; reads f32 q/k, writes split-bf16 q (hi+lo) and
// plain-bf16 k.  blockIdx.y: 0 -> Q, 1 -> K.
// =====================================================================
__global__ __launch_bounds__(256)
void rms_rope_split(const float* __restrict__ q, const float* __restrict__ k,
                    const float* __restrict__ qw, const float* __restrict__ kw,
                    const int* __restrict__ TTp,
                    unsigned short* __restrict__ qhi, unsigned short* __restrict__ qlo,
                    unsigned short* __restrict__ khi, int Ntok)
{
    const int idx = blockIdx.x * 256 + threadIdx.x;
    if (idx >= Ntok * H_NUM) return;
    const int h = idx & (H_NUM - 1);
    const int n = idx >> 4;

    const float* src;
    const float* w;
    if (blockIdx.y == 0) { src = q; w = qw; } else { src = k; w = kw; }
    const float* p = src + (size_t)n * C_DIM + h * DH;

    float x[DH];
    #pragma unroll
    for (int i = 0; i < DH / 4; ++i) *(float4*)&x[4 * i] = *(const float4*)&p[4 * i];

    float ss = 0.f;
    #pragma unroll
    for (int i = 0; i < DH; ++i) ss += x[i] * x[i];
    const float r = rsqrtf(ss * (1.0f / DH) + 1e-6f);
    #pragma unroll
    for (int i = 0; i < DH; ++i) x[i] *= r * w[i];

    const int TT = *TTp;
    if (n >= TT) {
        const int pidx = n - TT;
        const int NT = Ntok - TT;
        int hh = 23, ww = 40;
        if      (NT == 2640) { hh = 22; ww = 40; }
        else if (NT == 1530) { hh = 17; ww = 30; }
        else if (NT == 6120) { hh = 34; ww = 60; }
        else if (NT ==  660) { hh = 11; ww = 20; }
        float pos[3];
        pos[0] = (float)(pidx / (hh * ww));
        pos[1] = (float)((pidx / ww) % hh);
        pos[2] = (float)(pidx % ww);
        #pragma unroll
        for (int c = 0; c < 3; ++c) {
            #pragma unroll
            for (int j = 0; j < 16; ++j) {
                const float invf = exp2f(-0.83048202373f * (float)j);
                const float ang  = pos[c] * invf;
                const float cs = cosf(ang), sn = sinf(ang);
                const float a = x[32 * c + j], b = x[32 * c + j + 16];
                x[32 * c + j]      = a * cs - b * sn;
                x[32 * c + j + 16] = a * sn + b * cs;
            }
        }
    }

    const size_t off = (size_t)n * C_DIM + h * DH;
    if (blockIdx.y == 0) {
        #pragma unroll
        for (int i = 0; i < DH / 4; ++i) {
            unsigned short hb[4], lb[4];
            #pragma unroll
            for (int j = 0; j < 4; ++j) {
                hb[j] = f2bf_rne(x[4 * i + j]);
                lb[j] = f2bf_rne(x[4 * i + j] - bf2f(hb[j]));
            }
            *(ushort4*)&qhi[off + 4 * i] = *(ushort4*)hb;
            *(ushort4*)&qlo[off + 4 * i] = *(ushort4*)lb;
        }
    } else {
        #pragma unroll
        for (int i = 0; i < DH / 4; ++i) {
            unsigned short hb[4];
            #pragma unroll
            for (int j = 0; j < 4; ++j) hb[j] = f2bf_rne(x[4 * i + j]);
            *(ushort4*)&khi[off + 4 * i] = *(ushort4*)hb;
        }
    }
}

// =====================================================================
// V transpose: f32 V [N][C] -> bf16 Vt [H][96][vtStride] (zero-padded keys).
// One block = one (64-key, head) tile; LDS-tiled for coalesced writes.
// =====================================================================
__global__ __launch_bounds__(256)
void transpose_v(const float* __restrict__ V, unsigned short* __restrict__ vt,
                 int Ntok, int vtStride)
{
    __shared__ unsigned short tile[96 * 72];
    const int t  = threadIdx.x;
    const int k0 = blockIdx.x * 64;
    const int h  = blockIdx.y;

    #pragma unroll
    for (int it = 0; it < 6; ++it) {
        const int idx = t + 256 * it;        // 0..1535
        const int key = idx / 24, dg = idx % 24;
        float vv[4] = {0.f, 0.f, 0.f, 0.f};
        if (k0 + key < Ntok)
            *(float4*)vv = *(const float4*)&V[(size_t)(k0 + key) * C_DIM + h * DH + 4 * dg];
        #pragma unroll
        for (int j = 0; j < 4; ++j) tile[(4 * dg + j) * 72 + key] = f2bf_rne(vv[j]);
    }
    __syncthreads();
    #pragma unroll
    for (int it = 0; it < 3; ++it) {
        const int idx = t + 256 * it;        // 0..767
        const int d = idx >> 3, ck = idx & 7;
        *(bf16x8*)&vt[((size_t)h * DH + d) * vtStride + k0 + 8 * ck] =
            *(const bf16x8*)&tile[d * 72 + 8 * ck];
    }
}

// =====================================================================
// Flash attention with MFMA.  BM=BN=64; 4 waves, each owns a full
// 16-row Q strip.  Q split-bf16 in registers; K/V/P plain bf16.
// S = (Qh+Ql) K^T via 2 MFMAs/tile; P round-trips LDS (C->A layout).
// =====================================================================
__global__ __launch_bounds__(256)
void attn_mfma(const unsigned short* __restrict__ qhi,
               const unsigned short* __restrict__ qlo,
               const unsigned short* __restrict__ khi,
               const unsigned short* __restrict__ vt,
               float* __restrict__ O, int Ntok, int nKt, int vtStride)
{
    __shared__ unsigned short ldsK[64 * 96];   // [key][d]  (chunk-XOR swizzled)
    __shared__ unsigned short ldsV[96 * 72];   // [d][key]  stride 72
    __shared__ unsigned short ldsP[64 * 72];   // [qrow][key] stride 72

    const int t    = threadIdx.x;
    const int lane = t & 63;
    const int wv   = t >> 6;
    const int lrow = lane & 15;
    const int quad = lane >> 4;
    const int q0   = blockIdx.x * 64;
    const int h    = blockIdx.y;
    const size_t hoff = (size_t)h * DH;
    const float scale = 0.10206207261596577f;   // 96^-0.5

    // ---- Q fragments in registers (A-layout: m=lane&15, k=quad*8+j) ----
    bf16x8 qh[3], ql[3];
    {
        const int qr = q0 + wv * 16 + lrow;
        if (qr < Ntok) {
            const size_t base = (size_t)qr * C_DIM + hoff + quad * 8;
            #pragma unroll
            for (int kc = 0; kc < 3; ++kc) {
                qh[kc] = *(const bf16x8*)&qhi[base + 32 * kc];
                ql[kc] = *(const bf16x8*)&qlo[base + 32 * kc];
            }
        } else {
            const bf16x8 z = {0,0,0,0,0,0,0,0};
            #pragma unroll
            for (int kc = 0; kc < 3; ++kc) { qh[kc] = z; ql[kc] = z; }
        }
    }

    // staging geometry
    const int rK  = t >> 2;          // K row 0..63
    const int cK  = t & 3;           // base chunk
    const int swK = (rK >> 1) & 3;
    const int swf = (lrow >> 1) & 3; // frag-read swizzle

    float m_[4], l_[4];
    f32x4 oacc[6];
    #pragma unroll
    for (int p = 0; p < 4; ++p) { m_[p] = -1e30f; l_[p] = 0.f; }
    #pragma unroll
    for (int dt = 0; dt < 6; ++dt) oacc[dt] = (f32x4)0.f;

    for (int kt = 0; kt < nKt; ++kt) {
        const int k0 = kt * 64;
        __syncthreads();   // prior tile's K/V reads complete

        // ---- stage K (64x96 bf16, swizzled chunks) ----
        #pragma unroll
        for (int it = 0; it < 3; ++it) {
            bf16x8 v = {0,0,0,0,0,0,0,0};
            if (k0 + rK < Ntok)
                v = *(const bf16x8*)&khi[(size_t)(k0 + rK) * C_DIM + hoff + 8 * (cK + 4 * it)];
            *(bf16x8*)&ldsK[rK * 96 + 8 * (4 * it + (cK ^ swK))] = v;
        }
        // ---- stage V^T (96x64 bf16; vt is zero-padded past Ntok) ----
        #pragma unroll
        for (int it = 0; it < 3; ++it) {
            const int idx = t + 256 * it;
            const int dv = idx >> 3, ck = idx & 7;
            *(bf16x8*)&ldsV[dv * 72 + 8 * ck] =
                *(const bf16x8*)&vt[((size_t)h * DH + dv) * vtStride + k0 + 8 * ck];
        }
        __syncthreads();

        // ---- S = Q K^T  (4 col-tiles, 3 k-chunks, Q hi+lo) ----
        f32x4 sacc[4];
        #pragma unroll
        for (int nt = 0; nt < 4; ++nt) sacc[nt] = (f32x4)0.f;
        #pragma unroll
        for (int kc = 0; kc < 3; ++kc) {
            #pragma unroll
            for (int nt = 0; nt < 4; ++nt) {
                bf16x8 kb = *(const bf16x8*)&ldsK[(lrow + 16 * nt) * 96 + 8 * (4 * kc + (quad ^ swf))];
                sacc[nt] = __builtin_amdgcn_mfma_f32_16x16x32_bf16(qh[kc], kb, sacc[nt], 0, 0, 0);
                sacc[nt] = __builtin_amdgcn_mfma_f32_16x16x32_bf16(ql[kc], kb, sacc[nt], 0, 0, 0);
            }
        }

        // ---- online softmax (rows quad*4+p, cols lrow+16*nt) ----
        bool vld[4];
        #pragma unroll
        for (int nt = 0; nt < 4; ++nt) vld[nt] = (k0 + 16 * nt + lrow) < Ntok;
        #pragma unroll
        for (int p = 0; p < 4; ++p) {
            float sv[4]; float rmax = -1e30f;
            #pragma unroll
            for (int nt = 0; nt < 4; ++nt) {
                sv[nt] = vld[nt] ? sacc[nt][p] * scale : -1e30f;
                rmax = fmaxf(rmax, sv[nt]);
            }
            rmax = fmaxf(rmax, __shfl_xor(rmax, 1, 16));
            rmax = fmaxf(rmax, __shfl_xor(rmax, 2, 16));
            rmax = fmaxf(rmax, __shfl_xor(rmax, 4, 16));
            rmax = fmaxf(rmax, __shfl_xor(rmax, 8, 16));
            const float mnew  = fmaxf(m_[p], rmax);
            const float alpha = __expf(m_[p] - mnew);
            m_[p] = mnew;
            float rsum = 0.f;
            unsigned short prb[4];
            #pragma unroll
            for (int nt = 0; nt < 4; ++nt) {
                const float pr = __expf(sv[nt] - mnew);
                rsum += pr;
                prb[nt] = f2bf_rne(pr);
            }
            rsum += __shfl_xor(rsum, 1, 16);
            rsum += __shfl_xor(rsum, 2, 16);
            rsum += __shfl_xor(rsum, 4, 16);
            rsum += __shfl_xor(rsum, 8, 16);
            l_[p] = l_[p] * alpha + rsum;
            #pragma unroll
            for (int dt = 0; dt < 6; ++dt) oacc[dt][p] *= alpha;
            #pragma unroll
            for (int nt = 0; nt < 4; ++nt)
                ldsP[(wv * 16 + quad * 4 + p) * 72 + 16 * nt + lrow] = prb[nt];
        }
        // P written & read by the same wave only -> no barrier needed.

        // ---- O += P V  (6 d-tiles, 2 k-chunks) ----
        #pragma unroll
        for (int kc2 = 0; kc2 < 2; ++kc2) {
            bf16x8 pa = *(const bf16x8*)&ldsP[(wv * 16 + lrow) * 72 + 32 * kc2 + 8 * quad];
            #pragma unroll
            for (int dt = 0; dt < 6; ++dt) {
                bf16x8 vb = *(const bf16x8*)&ldsV[(16 * dt + lrow) * 72 + 32 * kc2 + 8 * quad];
                oacc[dt] = __builtin_amdgcn_mfma_f32_16x16x32_bf16(pa, vb, oacc[dt], 0, 0, 0);
            }
        }
    }

    // ---- epilogue: O / l ----
    #pragma unroll
    for (int p = 0; p < 4; ++p) {
        const int row = q0 + wv * 16 + quad * 4 + p;
        if (row >= Ntok) continue;
        const float rl = 1.0f / l_[p];
        #pragma unroll
        for (int dt = 0; dt < 6; ++dt)
            O[(size_t)row * C_DIM + hoff + 16 * dt + lrow] = oacc[dt][p] * rl;
    }
}

// =====================================================================
extern "C" void kernel_launch(void* const* d_in, const int* in_sizes, int n_in,
                              void* d_out, int out_size, void* d_ws, size_t ws_size,
                              hipStream_t stream)
{
    const float* x   = (const float*)d_in[0];
    const float* Wq  = (const float*)d_in[1];
    const float* bq  = (const float*)d_in[2];
    const float* Wk  = (const float*)d_in[3];
    const float* bk  = (const float*)d_in[4];
    const float* Wv  = (const float*)d_in[5];
    const float* bv  = (const float*)d_in[6];
    const float* qnw = (const float*)d_in[7];
    const float* knw = (const float*)d_in[8];
    const float* Wp  = (const float*)d_in[9];
    const float* bp  = (const float*)d_in[10];
    const int*   TTp = (const int*)d_in[11];

    const int Ntok = in_sizes[0] / C_DIM;        // 2866
    const int nKt  = (Ntok + 63) / 64;           // 45
    const int vtStride = nKt * 64;               // 2880
    const size_t NC = (size_t)Ntok * C_DIM;
    const size_t CC = (size_t)C_DIM * C_DIM;
    float* out = (float*)d_out;

    // workspace layout (~126 MB)
    float*          kbuf = (float*)d_ws;                      // NC f32
    float*          vbuf = kbuf + NC;                         // NC f32
    unsigned short* xhi  = (unsigned short*)(vbuf + NC);      // NC bf16
    unsigned short* xlo  = xhi + NC;                          // NC bf16
    unsigned short* wsp  = xlo + NC;                          // 8*CC bf16
    unsigned short* wqh = wsp + 0 * CC, *wql = wsp + 1 * CC;
    unsigned short* wkh = wsp + 2 * CC, *wkl = wsp + 3 * CC;
    unsigned short* wvh = wsp + 4 * CC, *wvl = wsp + 5 * CC;
    unsigned short* wph = wsp + 6 * CC, *wpl = wsp + 7 * CC;
    unsigned short* qhib = wsp + 8 * CC;                      // NC bf16
    unsigned short* qlob = qhib + NC;                         // NC bf16
    unsigned short* khib = qlob + NC;                         // NC bf16
    unsigned short* vtb  = khib + NC;                         // H*96*vtStride bf16
    float*          qbuf = out;                               // f32 Q (d_out)
    float*          obuf = (float*)xhi;                       // alias: x-splits dead after QKV
    unsigned short* ohi  = (unsigned short*)kbuf;             // alias: k f32 dead after rms
    unsigned short* olo  = ohi + NC;

    // 1) split conversions
    cvt_split<<<dim3((NC / 4 + 255) / 256), 256, 0, stream>>>(x,  xhi, xlo, (int)(NC / 4));
    cvt_split<<<dim3((CC / 4 + 255) / 256), 256, 0, stream>>>(Wq, wqh, wql, (int)(CC / 4));
    cvt_split<<<dim3((CC / 4 + 255) / 256), 256, 0, stream>>>(Wk, wkh, wkl, (int)(CC / 4));
    cvt_split<<<dim3((CC / 4 + 255) / 256), 256, 0, stream>>>(Wv, wvh, wvl, (int)(CC / 4));
    cvt_split<<<dim3((CC / 4 + 255) / 256), 256, 0, stream>>>(Wp, wph, wpl, (int)(CC / 4));

    // 2) fused QKV projection
    dim3 qkvgrid((Ntok + 127) / 128, C_DIM / 128, 3);
    gemm_mfma<<<qkvgrid, 256, 0, stream>>>(xhi, xlo,
        wqh, wql, bq, qbuf,
        wkh, wkl, bk, kbuf,
        wvh, wvl, bv, vbuf, Ntok);

    // 3) RMSNorm + RoPE -> split-bf16 Q, bf16 K
    const int nv = Ntok * H_NUM;
    rms_rope_split<<<dim3((nv + 255) / 256, 2), 256, 0, stream>>>(
        qbuf, kbuf, qnw, knw, TTp, qhib, qlob, khib, Ntok);

    // 4) V transpose -> bf16 [H][96][vtStride]
    transpose_v<<<dim3(nKt, H_NUM), 256, 0, stream>>>(vbuf, vtb, Ntok, vtStride);

    // 5) MFMA flash attention
    attn_mfma<<<dim3(nKt, H_NUM), 256, 0, stream>>>(
        qhib, qlob, khib, vtb, obuf, Ntok, nKt, vtStride);

    // 6) split O, output projection
    cvt_split<<<dim3((NC / 4 + 255) / 256), 256, 0, stream>>>(obuf, ohi, olo, (int)(NC / 4));
    dim3 pgrid((Ntok + 127) / 128, C_DIM / 128, 1);
    gemm_mfma<<<pgrid, 256, 0, stream>>>(ohi, olo,
        wph, wpl, bp, out,
        wph, wpl, bp, out,
        wph, wpl, bp, out, Ntok);
}